// Round 9
// baseline (413.615 us; speedup 1.0000x reference)
//
#include <hip/hip_runtime.h>
#include <math.h>

#define DMODEL 1024
#define NH 16
#define DHEAD 64
#define DFF 4096
#define BATCH 4
#define SEQ 2048
#define MROWS (BATCH * SEQ)   // 8192
#define LNEPS 1e-5f
#define NT (SEQ / 64)         // 32 kv tiles

typedef __attribute__((ext_vector_type(8))) short bf16x8;
typedef __attribute__((ext_vector_type(4))) float f32x4;
typedef __attribute__((ext_vector_type(16))) float f32x16;
typedef __attribute__((ext_vector_type(4))) unsigned int u32x4;

__device__ inline unsigned short f2bf(float f) {
  unsigned int u = __float_as_uint(f);
  unsigned int r = (u + 0x7fffu + ((u >> 16) & 1u)) >> 16;  // RNE
  return (unsigned short)r;
}

__device__ inline void gload16(const unsigned short* g, char* l) {
  __builtin_amdgcn_global_load_lds(
      (const __attribute__((address_space(1))) unsigned int*)g,
      (__attribute__((address_space(3))) unsigned int*)l, 16, 0, 0);
}

__device__ inline float fexp2(float x) {
  float r;
  asm("v_exp_f32 %0, %1" : "=v"(r) : "v"(x));
  return r;
}
__device__ inline unsigned int cvtpk(float lo, float hi) {
  unsigned int r;
  asm("v_cvt_pk_bf16_f32 %0, %1, %2" : "=v"(r) : "v"(lo), "v"(hi));
  return r;
}
__device__ inline void plswap(unsigned int& a, unsigned int& b) {
  asm("v_permlane32_swap_b32 %0, %1" : "+v"(a), "+v"(b));
}

// ---------------------------------------------------------------------------
// Embedding + positional encoding; dual output f32 (residual) + bf16 (GEMM A).
// ---------------------------------------------------------------------------
__global__ __launch_bounds__(256)
void embed_kernel(const int* __restrict__ tokens, const float* __restrict__ emb,
                  float* __restrict__ X, unsigned short* __restrict__ Xb) {
  const int HALF = DMODEL / 2;
  int idx = blockIdx.x * 256 + threadIdx.x;
  if (idx >= MROWS * HALF) return;
  int row = idx / HALF;
  int j = idx - row * HALF;
  int s = row & (SEQ - 1);
  int tok = tokens[row];
  float2 e = ((const float2*)(emb + (size_t)tok * DMODEL))[j];
  float denom = powf(10000.0f, (2.0f * (float)(2 * j)) / (float)DMODEL);
  float ang = (float)s / denom;
  float sn, cs;
  sincosf(ang, &sn, &cs);
  float2 o;
  o.x = e.x + sn;
  o.y = e.y + cs;
  ((float2*)(X + (size_t)row * DMODEL))[j] = o;
  ushort2 ob;
  ob.x = f2bf(o.x); ob.y = f2bf(o.y);
  ((ushort2*)(Xb + (size_t)row * DMODEL))[j] = ob;
}

// ---------------------------------------------------------------------------
// Fused fp32 -> bf16 conversion of all four weight matrices (one launch).
// ---------------------------------------------------------------------------
__global__ __launch_bounds__(256)
void cvt4_kernel(const float* __restrict__ a, const float* __restrict__ b,
                 const float* __restrict__ c, const float* __restrict__ d,
                 unsigned short* __restrict__ oa, unsigned short* __restrict__ ob,
                 unsigned short* __restrict__ oc, unsigned short* __restrict__ od) {
  int i = blockIdx.x * 256 + threadIdx.x;
  const float* src; unsigned short* dst; int off;
  if (i < 786432)       { src = a; dst = oa; off = 0; }
  else if (i < 1048576) { src = b; dst = ob; off = 786432; }
  else if (i < 2097152) { src = c; dst = oc; off = 1048576; }
  else                  { src = d; dst = od; off = 2097152; }
  int j = i - off;
  float4 v = ((const float4*)src)[j];
  ushort4 o;
  o.x = f2bf(v.x); o.y = f2bf(v.y); o.z = f2bf(v.z); o.w = f2bf(v.w);
  ((ushort4*)dst)[j] = o;
}

// ---------------------------------------------------------------------------
// gemm256: BM=BN=256, BK=64, 512 threads = 8 waves (2M x 4N), per-wave
// 128x64 output (acc[8][4] 16x16 frags). LDS 2 x 64KB double buffer.
// Lead-1 staging: ONE vmcnt(0)+barrier per K-tile at the top (loads were
// issued one full K-tile ago -> drain ~free), then stage kt+1 into the other
// buffer (race-free by disjoint buffers) and run 4 phases x 16 MFMA with
// setprio. B frags read once per K-tile; A frags per phase. Both-sides
// chunk-XOR swizzle (slot = chunk ^ (row&7)): linear gload_lds dest,
// pre-permuted global source, conflict-free b128 reads. XCD remap + 2x2
// supertile (2 A + 2 B panels = 2 MB ~ L2/XCD). Slab epilogue (aliases buf0
// after last K-tile, which reads buf1; nk is even) -> coalesced stores.
// ---------------------------------------------------------------------------
__device__ inline void stage256(const unsigned short* G, char* base, int row0,
                                int K, int kt, int t) {
#pragma unroll
  for (int i = 0; i < 4; ++i) {
    int g = i * 512 + t;
    int row = g >> 3, sl = g & 7;
    int c = sl ^ (row & 7);
    gload16(G + (size_t)(row0 + row) * K + kt * 64 + c * 8, base + g * 16);
  }
}

__global__ __launch_bounds__(512, 2)
void gemm256(const unsigned short* __restrict__ A, const unsigned short* __restrict__ B,
             const float* __restrict__ bias, const float* __restrict__ resid,
             float* __restrict__ Cf, unsigned short* __restrict__ Cb,
             int M, int N, int K, int relu) {
  extern __shared__ char smem[];   // 131072: 2 bufs x (A 32K + B 32K)

  const int t = threadIdx.x;
  const int lane = t & 63;
  const int wv = t >> 6;
  const int wm = wv >> 2;         // 0..1: A rows wm*128..+128
  const int wn = wv & 3;          // 0..3: B cols wn*64..+64
  const int fr = lane & 15;
  const int fq = lane >> 4;

  // XCD remap + 2x2 supertile (nwg % 8 == 0: 384 or 512)
  const int nwg = gridDim.x;
  const int orig = blockIdx.x;
  const int q8 = nwg >> 3;
  const int wgid = (orig & 7) * q8 + (orig >> 3);
  const int stid = wgid >> 2, within = wgid & 3;
  const int sm = within & 1, sn = within >> 1;
  const int Msup = M >> 9;                   // (M/256)/2 = 16
  const int stm = stid % Msup, stn = stid / Msup;
  const int m0 = (stm * 2 + sm) * 256;
  const int n0 = (stn * 2 + sn) * 256;

  f32x4 acc[8][4];
#pragma unroll
  for (int m = 0; m < 8; ++m)
#pragma unroll
    for (int n = 0; n < 4; ++n) acc[m][n] = (f32x4){0.f, 0.f, 0.f, 0.f};

  const int nk = K / 64;   // 16 (even)

  // prologue: stage kt0 -> buf0
  stage256(A, smem, m0, K, 0, t);
  stage256(B, smem + 32768, n0, K, 0, t);

  for (int kt = 0; kt < nk; ++kt) {
    const int buf = kt & 1;
    asm volatile("s_waitcnt vmcnt(0)" ::: "memory");   // kt's loads landed
    __builtin_amdgcn_s_barrier();                      // prev reads done, too
    if (kt + 1 < nk) {
      char* nxt = smem + ((buf ^ 1) << 16);
      stage256(A, nxt, m0, K, kt + 1, t);
      stage256(B, nxt + 32768, n0, K, kt + 1, t);
    }
    const unsigned short* Al = (const unsigned short*)(smem + (buf << 16));
    const unsigned short* Bl = (const unsigned short*)(smem + (buf << 16) + 32768);

    bf16x8 bfr[4][2];
#pragma unroll
    for (int n = 0; n < 4; ++n) {
      int brow = wn * 64 + n * 16 + fr;
#pragma unroll
      for (int ks = 0; ks < 2; ++ks)
        bfr[n][ks] = *(const bf16x8*)&Bl[brow * 64 + (((ks * 4 + fq) ^ (brow & 7)) * 8)];
    }
#pragma unroll
    for (int mp = 0; mp < 4; ++mp) {
      bf16x8 af[2][2];
#pragma unroll
      for (int mm = 0; mm < 2; ++mm) {
        int arow = wm * 128 + (mp * 2 + mm) * 16 + fr;
#pragma unroll
        for (int ks = 0; ks < 2; ++ks)
          af[mm][ks] = *(const bf16x8*)&Al[arow * 64 + (((ks * 4 + fq) ^ (arow & 7)) * 8)];
      }
      __builtin_amdgcn_s_setprio(1);
#pragma unroll
      for (int mm = 0; mm < 2; ++mm)
#pragma unroll
        for (int n = 0; n < 4; ++n)
#pragma unroll
          for (int ks = 0; ks < 2; ++ks)
            acc[mp * 2 + mm][n] = __builtin_amdgcn_mfma_f32_16x16x32_bf16(
                af[mm][ks], bfr[n][ks], acc[mp * 2 + mm][n], 0, 0, 0);
      __builtin_amdgcn_s_setprio(0);
    }
  }

  // epilogue: per-wave slab (16x68 f32) in buf0 region (last K-tile read buf1,
  // nk even; slab regions are wave-private and < 35KB total).
  float* slab = (float*)(smem + wv * 4352);
#pragma unroll
  for (int m = 0; m < 8; ++m) {
#pragma unroll
    for (int n = 0; n < 4; ++n)
#pragma unroll
      for (int j = 0; j < 4; ++j)
        slab[(fq * 4 + j) * 68 + n * 16 + fr] = acc[m][n][j];
    int rg0 = m0 + wm * 128 + m * 16;
#pragma unroll
    for (int it = 0; it < 4; ++it) {
      int u = it * 64 + lane;
      int row = u >> 4, seg = u & 15;
      float4 v = *(const float4*)&slab[row * 68 + seg * 4];
      int col = n0 + wn * 64 + seg * 4;
      float4 b4 = *(const float4*)&bias[col];
      v.x += b4.x; v.y += b4.y; v.z += b4.z; v.w += b4.w;
      if (relu) {
        v.x = fmaxf(v.x, 0.f); v.y = fmaxf(v.y, 0.f);
        v.z = fmaxf(v.z, 0.f); v.w = fmaxf(v.w, 0.f);
      }
      size_t idx = (size_t)(rg0 + row) * N + col;
      if (resid) {
        float4 r4 = *(const float4*)&resid[idx];
        v.x += r4.x; v.y += r4.y; v.z += r4.z; v.w += r4.w;
      }
      if (Cf) {
        *(float4*)&Cf[idx] = v;
      } else {
        ushort4 ob;
        ob.x = f2bf(v.x); ob.y = f2bf(v.y); ob.z = f2bf(v.z); ob.w = f2bf(v.w);
        *(ushort4*)&Cb[idx] = ob;
      }
    }
  }
}

// ---------------------------------------------------------------------------
// bf16 MFMA GEMM, BM=256 BN=128 (round-7 structure, kept for N=1024 shapes
// where it yields 256 blocks = full GPU).
// ---------------------------------------------------------------------------
#define AOFF(buf) ((buf) * 49152)
#define BOFF(buf) ((buf) * 49152 + 32768)

__device__ inline void stageA(const unsigned short* Ag, char* smem_, int buf,
                              int m0, int K, int kt, int wv, int lane) {
  int rl = lane >> 3, c = (lane & 7) ^ rl;
#pragma unroll
  for (int i = 0; i < 4; ++i) {
    int r0 = (wv * 4 + i) * 8;
    gload16(Ag + (size_t)(m0 + r0 + rl) * K + kt * 64 + c * 8,
            smem_ + AOFF(buf) + r0 * 128 + lane * 16);
  }
}
__device__ inline void stageB2(const unsigned short* Bg, char* smem_, int buf,
                               int n0, int K, int kt, int wv, int lane) {
  int rl = lane >> 3, c = (lane & 7) ^ rl;
#pragma unroll
  for (int i = 0; i < 2; ++i) {
    int r0 = (wv * 2 + i) * 8;
    gload16(Bg + (size_t)(n0 + r0 + rl) * K + kt * 64 + c * 8,
            smem_ + BOFF(buf) + r0 * 128 + lane * 16);
  }
}

#define VM6 asm volatile("s_waitcnt vmcnt(6)" ::: "memory")
#define VM0 asm volatile("s_waitcnt vmcnt(0)" ::: "memory")

#define DO_PHASE(buf, mb, LOADB, STAGE_STMT, WAIT_STMT)                         \
  {                                                                             \
    bf16x8 af[2][2];                                                            \
    _Pragma("unroll") for (int mm = 0; mm < 2; ++mm) {                          \
      int arow = wm * 64 + ((mb) + mm) * 16 + fr;                               \
      _Pragma("unroll") for (int ks = 0; ks < 2; ++ks) {                        \
        int slot = (ks * 4 + fq) ^ (arow & 7);                                  \
        af[mm][ks] = *(const bf16x8*)(smem + AOFF(buf) + arow * 128 + slot * 16); \
      }                                                                         \
    }                                                                           \
    if (LOADB) {                                                                \
      _Pragma("unroll") for (int n = 0; n < 4; ++n) {                           \
        int brow = wn * 64 + n * 16 + fr;                                       \
        _Pragma("unroll") for (int ks = 0; ks < 2; ++ks) {                      \
          int slot = (ks * 4 + fq) ^ (brow & 7);                                \
          bfr[n][ks] = *(const bf16x8*)(smem + BOFF(buf) + brow * 128 + slot * 16); \
        }                                                                       \
      }                                                                         \
    }                                                                           \
    STAGE_STMT;                                                                 \
    __builtin_amdgcn_sched_barrier(0);                                          \
    __builtin_amdgcn_s_barrier();                                               \
    __builtin_amdgcn_sched_barrier(0);                                          \
    __builtin_amdgcn_s_setprio(1);                                              \
    _Pragma("unroll") for (int mm = 0; mm < 2; ++mm)                            \
      _Pragma("unroll") for (int n = 0; n < 4; ++n)                             \
        _Pragma("unroll") for (int ks = 0; ks < 2; ++ks)                        \
          acc[(mb) + mm][n] = __builtin_amdgcn_mfma_f32_16x16x32_bf16(          \
              af[mm][ks], bfr[n][ks], acc[(mb) + mm][n], 0, 0, 0);              \
    __builtin_amdgcn_s_setprio(0);                                              \
    WAIT_STMT;                                                                  \
    __builtin_amdgcn_sched_barrier(0);                                          \
    __builtin_amdgcn_s_barrier();                                               \
    __builtin_amdgcn_sched_barrier(0);                                          \
  }

__global__ __launch_bounds__(512, 2)
void gemm8(const unsigned short* __restrict__ A, const unsigned short* __restrict__ B,
           const float* __restrict__ bias, const float* __restrict__ resid,
           float* __restrict__ Cf, unsigned short* __restrict__ Cb,
           int M, int N, int K, int relu) {
  extern __shared__ char smem[];   // 144 KB: 3 bufs x (A 32K + B 16K)

  const int t = threadIdx.x;
  const int lane = t & 63;
  const int wv = t >> 6;
  const int wm = wv >> 1;
  const int wn = wv & 1;
  const int fr = lane & 15;
  const int fq = lane >> 4;

  const int nwg = gridDim.x;
  const int orig = blockIdx.x;
  const int q8 = nwg >> 3;
  const int wgid = (orig & 7) * q8 + (orig >> 3);
  const int stid = wgid >> 4, within = wgid & 15;
  const int sm = within & 3, sn = within >> 2;
  const int Msup = M >> 10;
  const int stm = stid % Msup, stn = stid / Msup;
  const int m0 = (stm * 4 + sm) * 256;
  const int n0 = (stn * 4 + sn) * 128;

  f32x4 acc[4][4];
#pragma unroll
  for (int m = 0; m < 4; ++m)
#pragma unroll
    for (int n = 0; n < 4; ++n) acc[m][n] = (f32x4){0.f, 0.f, 0.f, 0.f};

  const int nk = K / 64;
  const int nj = nk / 2;

  stageB2(B, smem, 0, n0, K, 0, wv, lane);
  stageA (A, smem, 0, m0, K, 0, wv, lane);
  stageB2(B, smem, 1, n0, K, 1, wv, lane);
  stageA (A, smem, 1, m0, K, 1, wv, lane);
  VM6;
  __builtin_amdgcn_sched_barrier(0);
  __builtin_amdgcn_s_barrier();
  __builtin_amdgcn_sched_barrier(0);

  for (int j = 0; j < nj - 1; ++j) {
    const int k0 = 2 * j, k1 = 2 * j + 1;
    const int s0k = k0 + 2, s1k = k1 + 2;
    const int b0 = k0 % 3, b1 = k1 % 3;
    const int sb0 = s0k % 3, sb1 = s1k % 3;
    bf16x8 bfr[4][2];
    DO_PHASE(b0, 0, true,  stageB2(B, smem, sb0, n0, K, s0k, wv, lane), );
    DO_PHASE(b0, 2, false, stageA (A, smem, sb0, m0, K, s0k, wv, lane), VM6);
    DO_PHASE(b1, 0, true,  stageB2(B, smem, sb1, n0, K, s1k, wv, lane), );
    DO_PHASE(b1, 2, false, stageA (A, smem, sb1, m0, K, s1k, wv, lane), VM6);
  }
  {
    const int b0 = (nk - 2) % 3, b1 = (nk - 1) % 3;
    bf16x8 bfr[4][2];
    DO_PHASE(b0, 0, true,  , );
    DO_PHASE(b0, 2, false, , VM0);
    DO_PHASE(b1, 0, true,  , );
    DO_PHASE(b1, 2, false, , );
  }

  float* slab = (float*)(smem + wv * 4352);
#pragma unroll
  for (int m = 0; m < 4; ++m) {
#pragma unroll
    for (int n = 0; n < 4; ++n)
#pragma unroll
      for (int j = 0; j < 4; ++j)
        slab[(fq * 4 + j) * 68 + n * 16 + fr] = acc[m][n][j];
    int rg0 = m0 + wm * 64 + m * 16;
#pragma unroll
    for (int it = 0; it < 4; ++it) {
      int u = it * 64 + lane;
      int row = u >> 4, seg = u & 15;
      float4 v = *(const float4*)&slab[row * 68 + seg * 4];
      int col = n0 + wn * 64 + seg * 4;
      float4 b4 = *(const float4*)&bias[col];
      v.x += b4.x; v.y += b4.y; v.z += b4.z; v.w += b4.w;
      if (relu) {
        v.x = fmaxf(v.x, 0.f); v.y = fmaxf(v.y, 0.f);
        v.z = fmaxf(v.z, 0.f); v.w = fmaxf(v.w, 0.f);
      }
      size_t idx = (size_t)(rg0 + row) * N + col;
      if (resid) {
        float4 r4 = *(const float4*)&resid[idx];
        v.x += r4.x; v.y += r4.y; v.z += r4.z; v.w += r4.w;
      }
      if (Cf) {
        *(float4*)&Cf[idx] = v;
      } else {
        ushort4 ob;
        ob.x = f2bf(v.x); ob.y = f2bf(v.y); ob.z = f2bf(v.z); ob.w = f2bf(v.w);
        *(ushort4*)&Cb[idx] = ob;
      }
    }
  }
}

// ---------------------------------------------------------------------------
// V transpose: qkvb V-part [b,s][2048 + h*64 + d] -> vtb [(bh*64 + d)][s].
// 64x64 tiles via chunk-XOR LDS (loads/stores bank-audited <=2-way).
// ---------------------------------------------------------------------------
__global__ __launch_bounds__(256)
void vtrans_kernel(const unsigned short* __restrict__ qkvb, unsigned short* __restrict__ vtb) {
  __shared__ __align__(16) unsigned short tile[64][64];
  const int st = blockIdx.x;      // s-tile 0..31
  const int bh = blockIdx.y;      // 0..63
  const int b = bh >> 4, h = bh & 15;
  const int t = threadIdx.x;
#pragma unroll
  for (int p = 0; p < 2; ++p) {
    int item = p * 256 + t;
    int r = item >> 3, c8 = item & 7;
    const unsigned short* src =
        qkvb + (size_t)(b * SEQ + st * 64 + r) * (3 * DMODEL) + 2048 + h * 64 + c8 * 8;
    *(uint4*)&tile[r][(c8 ^ (r & 7)) * 8] = *(const uint4*)src;
  }
  __syncthreads();
#pragma unroll
  for (int p = 0; p < 2; ++p) {
    int item = p * 256 + t;
    int d = item & 63, s8 = item >> 6;
    unsigned short v[8];
#pragma unroll
    for (int e = 0; e < 8; ++e) {
      int s = s8 * 8 + e;
      v[e] = tile[s][(((d >> 3) ^ (s & 7)) * 8) + (d & 7)];
    }
    uint4 u;
    u.x = (unsigned int)v[0] | ((unsigned int)v[1] << 16);
    u.y = (unsigned int)v[2] | ((unsigned int)v[3] << 16);
    u.z = (unsigned int)v[4] | ((unsigned int)v[5] << 16);
    u.w = (unsigned int)v[6] | ((unsigned int)v[7] << 16);
    *(uint4*)(vtb + ((size_t)bh * 64 + d) * SEQ + st * 64 + s8 * 8) = u;
  }
}

// ---------------------------------------------------------------------------
// MFMA flash attention v5: v4 (swapped-operand 32x32, in-register softmax)
// with V staged via global_load_lds from the pre-transposed vtb — the
// per-tile V gather/pack/ds_write path is deleted.
// ---------------------------------------------------------------------------
__global__ __launch_bounds__(512, 4)
void attn_kernel(const unsigned short* __restrict__ qkv, const unsigned short* __restrict__ vtb,
                 unsigned short* __restrict__ ctxb) {
  __shared__ __align__(16) unsigned short Ks[2][64][64];
  __shared__ __align__(16) unsigned short Vts[2][64][64];
  __shared__ __align__(16) unsigned short Slab[8][32][64];

  const int t = threadIdx.x;
  const int lane = t & 63;
  const int wq = t >> 6;
  const int l31 = lane & 31;
  const int hi1 = lane >> 5;
  const int bid = blockIdx.x;
  const int bh = bid & 63;
  const int qt = bid >> 6;
  const int b = bh >> 4, h = bh & 15;
  const int q0 = qt * 256;

  const size_t RS = 3 * DMODEL;
  const unsigned short* qb = qkv + (size_t)b * SEQ * RS + h * DHEAD;
  const unsigned short* kb = qb + DMODEL;

  bf16x8 qf[4];
  {
    const unsigned short* qrow = qb + (size_t)(q0 + wq * 32 + l31) * RS;
#pragma unroll
    for (int s = 0; s < 4; ++s)
      qf[s] = *(const bf16x8*)(qrow + s * 16 + hi1 * 8);
  }

  // staging sources (wave wq stages rows [wq*8, wq*8+8) of each tile)
  const unsigned short* kgl =
      kb + (size_t)(wq * 8 + (lane >> 3)) * RS + ((lane & 7) ^ (lane >> 3)) * 8;
  const unsigned short* vgl =
      vtb + ((size_t)bh * 64 + wq * 8 + (lane >> 3)) * SEQ + ((lane & 7) ^ (lane >> 3)) * 8;

  f32x16 oacc[2] = {};
  float lacc = 0.f;

  gload16(kgl, (char*)&Ks[0][wq * 8][0]);
  gload16(vgl, (char*)&Vts[0][wq * 8][0]);
  __syncthreads();

  const float C = 0.18033688011112042f;   // 0.125 * log2(e)

  for (int kt = 0; kt < NT; ++kt) {
    const int cur = kt & 1;
    if (kt + 1 < NT) {
      gload16(kgl + (size_t)(kt + 1) * 64 * RS, (char*)&Ks[cur ^ 1][wq * 8][0]);
      gload16(vgl + (size_t)(kt + 1) * 64, (char*)&Vts[cur ^ 1][wq * 8][0]);
    }

    f32x16 sacc[2] = {};
    __builtin_amdgcn_s_setprio(1);
#pragma unroll
    for (int s = 0; s < 4; ++s) {
#pragma unroll
      for (int kvt = 0; kvt < 2; ++kvt) {
        int row = kvt * 32 + l31;
        bf16x8 kf = *(const bf16x8*)&Ks[cur][row][(((2 * s + hi1) ^ (row & 7)) * 8)];
        sacc[kvt] = __builtin_amdgcn_mfma_f32_32x32x16_bf16(kf, qf[s], sacc[kvt], 0, 0, 0);
      }
    }
    __builtin_amdgcn_s_setprio(0);

#pragma unroll
    for (int kvt = 0; kvt < 2; ++kvt) {
      float p[16];
#pragma unroll
      for (int r = 0; r < 16; ++r) p[r] = fexp2(sacc[kvt][r] * C);
      float ps = 0.f;
#pragma unroll
      for (int r = 0; r < 16; ++r) ps += p[r];
      lacc += ps;
#pragma unroll
      for (int half = 0; half < 2; ++half) {
        const int lo = half * 8;
        unsigned int x0 = cvtpk(p[lo + 0], p[lo + 1]);
        unsigned int x1 = cvtpk(p[lo + 2], p[lo + 3]);
        unsigned int y0 = cvtpk(p[lo + 4], p[lo + 5]);
        unsigned int y1 = cvtpk(p[lo + 6], p[lo + 7]);
        plswap(x0, y0);
        plswap(x1, y1);
        bf16x8 pa = __builtin_bit_cast(bf16x8, (u32x4){x0, x1, y0, y1});
        const int s2 = kvt * 2 + half;
        __builtin_amdgcn_s_setprio(1);
#pragma unroll
        for (int dt = 0; dt < 2; ++dt) {
          int vrow = dt * 32 + l31;
          bf16x8 vf = *(const bf16x8*)&Vts[cur][vrow][(((2 * s2 + hi1) ^ (vrow & 7)) * 8)];
          oacc[dt] = __builtin_amdgcn_mfma_f32_32x32x16_bf16(pa, vf, oacc[dt], 0, 0, 0);
        }
        __builtin_amdgcn_s_setprio(0);
      }
    }
    __syncthreads();   // drains this iter's gloads (full tile of flight)
  }

  lacc += __shfl_xor(lacc, 32);
  float inv = 1.0f / lacc;

  float iv[16];
#pragma unroll
  for (int r = 0; r < 16; ++r)
    iv[r] = __shfl(inv, (r & 3) + 8 * (r >> 2) + 4 * hi1);

#pragma unroll
  for (int dt = 0; dt < 2; ++dt) {
    const int chunk = dt * 4 + (l31 >> 3);
    const int e7 = l31 & 7;
#pragma unroll
    for (int r = 0; r < 16; ++r) {
      int qp = (r & 3) + 8 * (r >> 2) + 4 * hi1;
      Slab[wq][qp][((chunk ^ (qp & 7)) * 8) + e7] = f2bf(oacc[dt][r] * iv[r]);
    }
  }
#pragma unroll
  for (int it = 0; it < 4; ++it) {
    int u = it * 64 + lane;
    int row = u >> 3, s = u & 7;
    uint4 v = *(const uint4*)&Slab[wq][row][((s ^ (row & 7)) * 8)];
    *(uint4*)(ctxb + (size_t)(b * SEQ + q0 + wq * 32 + row) * DMODEL + h * DHEAD + s * 8) = v;
  }
}

// ---------------------------------------------------------------------------
// LayerNorm with optional secondary bf16 output.
// ---------------------------------------------------------------------------
__global__ __launch_bounds__(256)
void ln_kernel(const float* __restrict__ Z, const float* __restrict__ g,
               const float* __restrict__ bta, float* __restrict__ Y,
               unsigned short* __restrict__ Yb) {
  const int row = blockIdx.x;
  const float4* z4 = (const float4*)(Z + (size_t)row * DMODEL);
  float4 v = z4[threadIdx.x];
  float s = v.x + v.y + v.z + v.w;
  float ss = fmaf(v.x, v.x, fmaf(v.y, v.y, fmaf(v.z, v.z, v.w * v.w)));
#pragma unroll
  for (int o = 32; o >= 1; o >>= 1) {
    s += __shfl_xor(s, o);
    ss += __shfl_xor(ss, o);
  }
  __shared__ float red[8];
  int w = threadIdx.x >> 6;
  if ((threadIdx.x & 63) == 0) { red[w] = s; red[4 + w] = ss; }
  __syncthreads();
  s = red[0] + red[1] + red[2] + red[3];
  ss = red[4] + red[5] + red[6] + red[7];
  float mu = s * (1.0f / DMODEL);
  float var = ss * (1.0f / DMODEL) - mu * mu;
  float rs = rsqrtf(var + LNEPS);
  float4 gg = ((const float4*)g)[threadIdx.x];
  float4 bb = ((const float4*)bta)[threadIdx.x];
  float4 o;
  o.x = (v.x - mu) * rs * gg.x + bb.x;
  o.y = (v.y - mu) * rs * gg.y + bb.y;
  o.z = (v.z - mu) * rs * gg.z + bb.z;
  o.w = (v.w - mu) * rs * gg.w + bb.w;
  ((float4*)(Y + (size_t)row * DMODEL))[threadIdx.x] = o;
  if (Yb) {
    ushort4 ob;
    ob.x = f2bf(o.x); ob.y = f2bf(o.y); ob.z = f2bf(o.z); ob.w = f2bf(o.w);
    ((ushort4*)(Yb + (size_t)row * DMODEL))[threadIdx.x] = ob;
  }
}

// ---------------------------------------------------------------------------
extern "C" void kernel_launch(void* const* d_in, const int* in_sizes, int n_in,
                              void* d_out, int out_size, void* d_ws, size_t ws_size,
                              hipStream_t stream) {
  const int* tokens       = (const int*)d_in[0];
  const float* emb        = (const float*)d_in[1];
  const float* in_proj_w  = (const float*)d_in[2];
  const float* in_proj_b  = (const float*)d_in[3];
  const float* out_proj_w = (const float*)d_in[4];
  const float* out_proj_b = (const float*)d_in[5];
  const float* w1         = (const float*)d_in[6];
  const float* b1         = (const float*)d_in[7];
  const float* w2         = (const float*)d_in[8];
  const float* b2         = (const float*)d_in[9];
  const float* g1         = (const float*)d_in[10];
  const float* beta1      = (const float*)d_in[11];
  const float* g2         = (const float*)d_in[12];
  const float* beta2      = (const float*)d_in[13];
  float* out = (float*)d_out;

  char* ws = (char*)d_ws;
  const size_t MB = 1ull << 20;
  // Memory plan (peak 184 MiB):
  //   inwb  [0,6) outwb [6,8) w1b [8,16) w2b [16,24)   bf16 weights
  //   x     [24,56)   f32 embed (residual)
  //   xb    [56,72)   bf16 x (qkv A); ctxb reuses after attn
  //   qkvb  [72,120)  bf16 qkv (Q,K used; V region source for vtrans)
  //   vtb   [120,136) bf16 V^T [(bh*64+d)][s]  (live vtrans..attn;
  //                   ffbb reuses [120,184) from ff1 on — disjoint in time)
  //   h     [72,104)  f32 (reuses qkvb), hb [104,120) bf16
  //   ffbb  [120,184) bf16 relu(ff1)
  //   y2    [24,56)   f32 (reuses x)
  unsigned short* inwb  = (unsigned short*)(ws + 0 * MB);
  unsigned short* outwb = (unsigned short*)(ws + 6 * MB);
  unsigned short* w1b   = (unsigned short*)(ws + 8 * MB);
  unsigned short* w2b   = (unsigned short*)(ws + 16 * MB);
  float* x              = (float*)(ws + 24 * MB);
  unsigned short* xb    = (unsigned short*)(ws + 56 * MB);
  unsigned short* qkvb  = (unsigned short*)(ws + 72 * MB);
  unsigned short* vtb   = (unsigned short*)(ws + 120 * MB);
  unsigned short* ctxb  = (unsigned short*)(ws + 56 * MB);
  float* h              = (float*)(ws + 72 * MB);
  unsigned short* hb    = (unsigned short*)(ws + 104 * MB);
  unsigned short* ffbb  = (unsigned short*)(ws + 120 * MB);
  float* y2             = (float*)(ws + 24 * MB);

  const size_t GLDS8 = 147456;    // gemm8: 144 KB
  const size_t GLDS256 = 131072;  // gemm256: 128 KB

  embed_kernel<<<(MROWS * (DMODEL / 2) + 255) / 256, 256, 0, stream>>>(tokens, emb, x, xb);
  cvt4_kernel<<<12288, 256, 0, stream>>>(in_proj_w, out_proj_w, w1, w2,
                                         inwb, outwb, w1b, w2b);
  // qkv = x @ in_proj_w^T + b  (bf16 out)   [384 blocks]
  gemm256<<<(MROWS / 256) * (3 * DMODEL / 256), 512, GLDS256, stream>>>(
      xb, inwb, in_proj_b, nullptr, nullptr, qkvb, MROWS, 3 * DMODEL, DMODEL, 0);
  // V^T pre-transpose for attention staging
  vtrans_kernel<<<dim3(SEQ / 64, BATCH * NH), 256, 0, stream>>>(qkvb, vtb);
  // flash attention v5 -> ctxb (bf16)
  attn_kernel<<<(SEQ / 256) * (BATCH * NH), 512, 0, stream>>>(qkvb, vtb, ctxb);
  // h = ctx @ out_proj_w^T + b + x  (f32 out)   [256 blocks]
  gemm8<<<(MROWS / 256) * (DMODEL / 128), 512, GLDS8, stream>>>(
      ctxb, outwb, out_proj_b, x, h, nullptr, MROWS, DMODEL, DMODEL, 0);
  ln_kernel<<<MROWS, 256, 0, stream>>>(h, g1, beta1, h, hb);
  // ffb = relu(h @ w1^T + b1)  (bf16 out)   [512 blocks]
  gemm256<<<(MROWS / 256) * (DFF / 256), 512, GLDS256, stream>>>(
      hb, w1b, b1, nullptr, nullptr, ffbb, MROWS, DFF, DMODEL, 1);
  // y2 = ffb @ w2^T + b2 + h  (f32 out)   [256 blocks]
  gemm8<<<(MROWS / 256) * (DMODEL / 128), 512, GLDS8, stream>>>(
      ffbb, w2b, b2, h, y2, nullptr, MROWS, DMODEL, DFF, 0);
  ln_kernel<<<MROWS, 256, 0, stream>>>(y2, g2, beta2, out, nullptr);
}

// Round 10
// 400.917 us; speedup vs baseline: 1.0317x; 1.0317x over previous
//
#include <hip/hip_runtime.h>
#include <math.h>

#define DMODEL 1024
#define NH 16
#define DHEAD 64
#define DFF 4096
#define BATCH 4
#define SEQ 2048
#define MROWS (BATCH * SEQ)   // 8192
#define LNEPS 1e-5f
#define NT (SEQ / 64)         // 32 kv tiles

typedef __attribute__((ext_vector_type(8))) short bf16x8;
typedef __attribute__((ext_vector_type(4))) float f32x4;
typedef __attribute__((ext_vector_type(16))) float f32x16;
typedef __attribute__((ext_vector_type(4))) unsigned int u32x4;

__device__ inline unsigned short f2bf(float f) {
  unsigned int u = __float_as_uint(f);
  unsigned int r = (u + 0x7fffu + ((u >> 16) & 1u)) >> 16;  // RNE
  return (unsigned short)r;
}

__device__ inline void gload16(const unsigned short* g, char* l) {
  __builtin_amdgcn_global_load_lds(
      (const __attribute__((address_space(1))) unsigned int*)g,
      (__attribute__((address_space(3))) unsigned int*)l, 16, 0, 0);
}

__device__ inline float fexp2(float x) {
  float r;
  asm("v_exp_f32 %0, %1" : "=v"(r) : "v"(x));
  return r;
}
__device__ inline unsigned int cvtpk(float lo, float hi) {
  unsigned int r;
  asm("v_cvt_pk_bf16_f32 %0, %1, %2" : "=v"(r) : "v"(lo), "v"(hi));
  return r;
}
__device__ inline void plswap(unsigned int& a, unsigned int& b) {
  asm("v_permlane32_swap_b32 %0, %1" : "+v"(a), "+v"(b));
}

// ---------------------------------------------------------------------------
// Embedding + positional encoding; dual output f32 (residual) + bf16 (GEMM A).
// ---------------------------------------------------------------------------
__global__ __launch_bounds__(256)
void embed_kernel(const int* __restrict__ tokens, const float* __restrict__ emb,
                  float* __restrict__ X, unsigned short* __restrict__ Xb) {
  const int HALF = DMODEL / 2;
  int idx = blockIdx.x * 256 + threadIdx.x;
  if (idx >= MROWS * HALF) return;
  int row = idx / HALF;
  int j = idx - row * HALF;
  int s = row & (SEQ - 1);
  int tok = tokens[row];
  float2 e = ((const float2*)(emb + (size_t)tok * DMODEL))[j];
  float denom = powf(10000.0f, (2.0f * (float)(2 * j)) / (float)DMODEL);
  float ang = (float)s / denom;
  float sn, cs;
  sincosf(ang, &sn, &cs);
  float2 o;
  o.x = e.x + sn;
  o.y = e.y + cs;
  ((float2*)(X + (size_t)row * DMODEL))[j] = o;
  ushort2 ob;
  ob.x = f2bf(o.x); ob.y = f2bf(o.y);
  ((ushort2*)(Xb + (size_t)row * DMODEL))[j] = ob;
}

// ---------------------------------------------------------------------------
// Fused fp32 -> bf16 conversion of all four weight matrices (one launch).
// ---------------------------------------------------------------------------
__global__ __launch_bounds__(256)
void cvt4_kernel(const float* __restrict__ a, const float* __restrict__ b,
                 const float* __restrict__ c, const float* __restrict__ d,
                 unsigned short* __restrict__ oa, unsigned short* __restrict__ ob,
                 unsigned short* __restrict__ oc, unsigned short* __restrict__ od) {
  int i = blockIdx.x * 256 + threadIdx.x;
  const float* src; unsigned short* dst; int off;
  if (i < 786432)       { src = a; dst = oa; off = 0; }
  else if (i < 1048576) { src = b; dst = ob; off = 786432; }
  else if (i < 2097152) { src = c; dst = oc; off = 1048576; }
  else                  { src = d; dst = od; off = 2097152; }
  int j = i - off;
  float4 v = ((const float4*)src)[j];
  ushort4 o;
  o.x = f2bf(v.x); o.y = f2bf(v.y); o.z = f2bf(v.z); o.w = f2bf(v.w);
  ((ushort4*)dst)[j] = o;
}

// ---------------------------------------------------------------------------
// gemm8p: m201-style 8-phase 256x256 GEMM. BK=64, 512 threads = 8 waves
// (2M x 4N), per-wave 128x64 (acc[8][4]). LDS 2 x 64KB dbuf (tile kt -> buf
// kt&1: A 32KB + B 32KB, each 2 halves of 128 rows).
// Per phase: {ds-read subtile; stage 1 half-tile (2 gload_lds); barrier;
// lgkmcnt(0)+sched_barrier; setprio(1); 16 MFMA (one quadrant x K=64);
// setprio(0); [vmcnt(4) at P4/P8]; barrier}.
// Staging schedule (iter j = K-tiles 2j,2j+1): P1/P2: A(2j+1) halves;
// P3/P4: B(2j+2); P5/P6: A(2j+2); P7/P8: B(2j+3). Each half staged >=1 phase
// after its last read (A(k) reads end P3/P7; B(k) end P2/P6). vmcnt(4)
// accounting (2 loads/phase): P4-wait lands {B(2j+1),A(2j+1)} for P5-P7;
// P8-wait lands {B(2j+2),A(2j+2)} for next P1-P3. Prologue: A(0),B(0),B(1)
// + vmcnt(4). Last iter: stage only A(nk-1) at P1/P2, vmcnt(0) at P4.
// Both-sides chunk-XOR swizzle (slot = chunk ^ (row&7)). XCD remap + 2x2
// supertile. Slab epilogue (aliases buf0; last reads were buf1).
// ---------------------------------------------------------------------------
__device__ inline void sthalf8(const unsigned short* G, int grow0, int K, int kt,
                               char* smem_, int isB, int half, int t) {
  char* dst = smem_ + ((kt & 1) * 65536) + isB * 32768 + half * 16384;
#pragma unroll
  for (int i = 0; i < 2; ++i) {
    int g = i * 512 + t;
    int r = g >> 3, sl = g & 7;
    int c = sl ^ (r & 7);
    gload16(G + (size_t)(grow0 + half * 128 + r) * K + kt * 64 + c * 8, dst + g * 16);
  }
}

#define VM4_ asm volatile("s_waitcnt vmcnt(4)" ::: "memory")
#define VM0_ asm volatile("s_waitcnt vmcnt(0)" ::: "memory")

#define PHASE8(bufofs, MG, NP, LA, LB, STAGE_STMT, WAIT_STMT)                   \
  {                                                                             \
    if (LA) {                                                                   \
      _Pragma("unroll") for (int m = 0; m < 4; ++m) {                           \
        int arow = wm * 128 + (MG) * 64 + m * 16 + fr;                          \
        _Pragma("unroll") for (int ks = 0; ks < 2; ++ks)                        \
          af[m][ks] = *(const bf16x8*)(smem + (bufofs) + arow * 128 +           \
                        (((ks * 4 + fq) ^ (arow & 7)) * 16));                   \
      }                                                                         \
    }                                                                           \
    if (LB) {                                                                   \
      _Pragma("unroll") for (int nn = 0; nn < 2; ++nn) {                        \
        int n = (NP) * 2 + nn;                                                  \
        int brow = wn * 64 + n * 16 + fr;                                       \
        _Pragma("unroll") for (int ks = 0; ks < 2; ++ks)                        \
          bf[(NP) * 2 + nn][ks] = *(const bf16x8*)(smem + (bufofs) + 32768 +    \
                        brow * 128 + (((ks * 4 + fq) ^ (brow & 7)) * 16));      \
      }                                                                         \
    }                                                                           \
    STAGE_STMT;                                                                 \
    __builtin_amdgcn_sched_barrier(0);                                          \
    __builtin_amdgcn_s_barrier();                                               \
    asm volatile("s_waitcnt lgkmcnt(0)" ::: "memory");                          \
    __builtin_amdgcn_sched_barrier(0);                                          \
    __builtin_amdgcn_s_setprio(1);                                              \
    _Pragma("unroll") for (int m = 0; m < 4; ++m)                               \
      _Pragma("unroll") for (int nn = 0; nn < 2; ++nn)                          \
        _Pragma("unroll") for (int ks = 0; ks < 2; ++ks)                        \
          acc[(MG) * 4 + m][(NP) * 2 + nn] =                                    \
              __builtin_amdgcn_mfma_f32_16x16x32_bf16(                          \
                  af[m][ks], bf[(NP) * 2 + nn][ks],                             \
                  acc[(MG) * 4 + m][(NP) * 2 + nn], 0, 0, 0);                   \
    __builtin_amdgcn_s_setprio(0);                                              \
    WAIT_STMT;                                                                  \
    __builtin_amdgcn_sched_barrier(0);                                          \
    __builtin_amdgcn_s_barrier();                                               \
    __builtin_amdgcn_sched_barrier(0);                                          \
  }

__global__ __launch_bounds__(512, 2)
void gemm8p(const unsigned short* __restrict__ A, const unsigned short* __restrict__ B,
            const float* __restrict__ bias, const float* __restrict__ resid,
            float* __restrict__ Cf, unsigned short* __restrict__ Cb,
            int M, int N, int K, int relu) {
  extern __shared__ char smem[];   // 131072: 2 bufs x (A 32K + B 32K)

  const int t = threadIdx.x;
  const int lane = t & 63;
  const int wv = t >> 6;
  const int wm = wv >> 2;         // 0..1: rows wm*128..+128
  const int wn = wv & 3;          // 0..3: cols wn*64..+64
  const int fr = lane & 15;
  const int fq = lane >> 4;

  // XCD remap + 2x2 supertile (nwg % 8 == 0: 384 or 512)
  const int nwg = gridDim.x;
  const int orig = blockIdx.x;
  const int q8 = nwg >> 3;
  const int wgid = (orig & 7) * q8 + (orig >> 3);
  const int stid = wgid >> 2, within = wgid & 3;
  const int sm = within & 1, sn = within >> 1;
  const int Msup = M >> 9;                   // 16
  const int stm = stid % Msup, stn = stid / Msup;
  const int m0 = (stm * 2 + sm) * 256;
  const int n0 = (stn * 2 + sn) * 256;

  f32x4 acc[8][4];
#pragma unroll
  for (int m = 0; m < 8; ++m)
#pragma unroll
    for (int n = 0; n < 4; ++n) acc[m][n] = (f32x4){0.f, 0.f, 0.f, 0.f};

  const int nk = K / 64;   // 16
  const int nj = nk / 2;   // 8

  // prologue: A(0) h0,h1; B(0) h0,h1; B(1) h0,h1  (12 wave-loads)
  sthalf8(A, m0, K, 0, smem, 0, 0, t);
  sthalf8(A, m0, K, 0, smem, 0, 1, t);
  sthalf8(B, n0, K, 0, smem, 1, 0, t);
  sthalf8(B, n0, K, 0, smem, 1, 1, t);
  sthalf8(B, n0, K, 1, smem, 1, 0, t);
  sthalf8(B, n0, K, 1, smem, 1, 1, t);
  VM4_;
  __builtin_amdgcn_sched_barrier(0);
  __builtin_amdgcn_s_barrier();
  __builtin_amdgcn_sched_barrier(0);

  bf16x8 af[4][2];
  bf16x8 bf[4][2];

  for (int j = 0; j < nj; ++j) {
    const bool st = (j + 1 < nj);
    // P1: af(mg0,k0) + bf(np0,k0); stage A_h0(2j+1)
    PHASE8(0, 0, 0, 1, 1, sthalf8(A, m0, K, 2 * j + 1, smem, 0, 0, t), );
    // P2: bf(np1,k0); stage A_h1(2j+1)
    PHASE8(0, 0, 1, 0, 1, sthalf8(A, m0, K, 2 * j + 1, smem, 0, 1, t), );
    // P3: af(mg1,k0); stage B_h0(2j+2)
    PHASE8(0, 1, 1, 1, 0,
           if (st) sthalf8(B, n0, K, 2 * j + 2, smem, 1, 0, t), );
    // P4: (no reads); stage B_h1(2j+2); wait
    PHASE8(0, 1, 0, 0, 0,
           if (st) sthalf8(B, n0, K, 2 * j + 2, smem, 1, 1, t),
           { if (st) { VM4_; } else { VM0_; } });
    // P5: af(mg0,k1) + bf(np0,k1); stage A_h0(2j+2)
    PHASE8(65536, 0, 0, 1, 1,
           if (st) sthalf8(A, m0, K, 2 * j + 2, smem, 0, 0, t), );
    // P6: bf(np1,k1); stage A_h1(2j+2)
    PHASE8(65536, 0, 1, 0, 1,
           if (st) sthalf8(A, m0, K, 2 * j + 2, smem, 0, 1, t), );
    // P7: af(mg1,k1); stage B_h0(2j+3)
    PHASE8(65536, 1, 1, 1, 0,
           if (st) sthalf8(B, n0, K, 2 * j + 3, smem, 1, 0, t), );
    // P8: (no reads); stage B_h1(2j+3); wait
    PHASE8(65536, 1, 0, 0, 0,
           if (st) sthalf8(B, n0, K, 2 * j + 3, smem, 1, 1, t),
           { if (st) { VM4_; } });
  }

  // epilogue: per-wave slab (16x68 f32), coalesced vector stores.
  float* slab = (float*)(smem + wv * 4352);
#pragma unroll
  for (int m = 0; m < 8; ++m) {
#pragma unroll
    for (int n = 0; n < 4; ++n)
#pragma unroll
      for (int j = 0; j < 4; ++j)
        slab[(fq * 4 + j) * 68 + n * 16 + fr] = acc[m][n][j];
    int rg0 = m0 + wm * 128 + m * 16;
#pragma unroll
    for (int it = 0; it < 4; ++it) {
      int u = it * 64 + lane;
      int row = u >> 4, seg = u & 15;
      float4 v = *(const float4*)&slab[row * 68 + seg * 4];
      int col = n0 + wn * 64 + seg * 4;
      float4 b4 = *(const float4*)&bias[col];
      v.x += b4.x; v.y += b4.y; v.z += b4.z; v.w += b4.w;
      if (relu) {
        v.x = fmaxf(v.x, 0.f); v.y = fmaxf(v.y, 0.f);
        v.z = fmaxf(v.z, 0.f); v.w = fmaxf(v.w, 0.f);
      }
      size_t idx = (size_t)(rg0 + row) * N + col;
      if (resid) {
        float4 r4 = *(const float4*)&resid[idx];
        v.x += r4.x; v.y += r4.y; v.z += r4.z; v.w += r4.w;
      }
      if (Cf) {
        *(float4*)&Cf[idx] = v;
      } else {
        ushort4 ob;
        ob.x = f2bf(v.x); ob.y = f2bf(v.y); ob.z = f2bf(v.z); ob.w = f2bf(v.w);
        *(ushort4*)&Cb[idx] = ob;
      }
    }
  }
}

// ---------------------------------------------------------------------------
// bf16 MFMA GEMM, BM=256 BN=128 (round-7 structure; N=1024 shapes -> 256
// blocks = full GPU).
// ---------------------------------------------------------------------------
#define AOFF(buf) ((buf) * 49152)
#define BOFF(buf) ((buf) * 49152 + 32768)

__device__ inline void stageA(const unsigned short* Ag, char* smem_, int buf,
                              int m0, int K, int kt, int wv, int lane) {
  int rl = lane >> 3, c = (lane & 7) ^ rl;
#pragma unroll
  for (int i = 0; i < 4; ++i) {
    int r0 = (wv * 4 + i) * 8;
    gload16(Ag + (size_t)(m0 + r0 + rl) * K + kt * 64 + c * 8,
            smem_ + AOFF(buf) + r0 * 128 + lane * 16);
  }
}
__device__ inline void stageB2(const unsigned short* Bg, char* smem_, int buf,
                               int n0, int K, int kt, int wv, int lane) {
  int rl = lane >> 3, c = (lane & 7) ^ rl;
#pragma unroll
  for (int i = 0; i < 2; ++i) {
    int r0 = (wv * 2 + i) * 8;
    gload16(Bg + (size_t)(n0 + r0 + rl) * K + kt * 64 + c * 8,
            smem_ + BOFF(buf) + r0 * 128 + lane * 16);
  }
}

#define VM6 asm volatile("s_waitcnt vmcnt(6)" ::: "memory")
#define VM0 asm volatile("s_waitcnt vmcnt(0)" ::: "memory")

#define DO_PHASE(buf, mb, LOADB, STAGE_STMT, WAIT_STMT)                         \
  {                                                                             \
    bf16x8 af[2][2];                                                            \
    _Pragma("unroll") for (int mm = 0; mm < 2; ++mm) {                          \
      int arow = wm * 64 + ((mb) + mm) * 16 + fr;                               \
      _Pragma("unroll") for (int ks = 0; ks < 2; ++ks) {                        \
        int slot = (ks * 4 + fq) ^ (arow & 7);                                  \
        af[mm][ks] = *(const bf16x8*)(smem + AOFF(buf) + arow * 128 + slot * 16); \
      }                                                                         \
    }                                                                           \
    if (LOADB) {                                                                \
      _Pragma("unroll") for (int n = 0; n < 4; ++n) {                           \
        int brow = wn * 64 + n * 16 + fr;                                       \
        _Pragma("unroll") for (int ks = 0; ks < 2; ++ks) {                      \
          int slot = (ks * 4 + fq) ^ (brow & 7);                                \
          bfr[n][ks] = *(const bf16x8*)(smem + BOFF(buf) + brow * 128 + slot * 16); \
        }                                                                       \
      }                                                                         \
    }                                                                           \
    STAGE_STMT;                                                                 \
    __builtin_amdgcn_sched_barrier(0);                                          \
    __builtin_amdgcn_s_barrier();                                               \
    __builtin_amdgcn_sched_barrier(0);                                          \
    __builtin_amdgcn_s_setprio(1);                                              \
    _Pragma("unroll") for (int mm = 0; mm < 2; ++mm)                            \
      _Pragma("unroll") for (int n = 0; n < 4; ++n)                             \
        _Pragma("unroll") for (int ks = 0; ks < 2; ++ks)                        \
          acc[(mb) + mm][n] = __builtin_amdgcn_mfma_f32_16x16x32_bf16(          \
              af[mm][ks], bfr[n][ks], acc[(mb) + mm][n], 0, 0, 0);              \
    __builtin_amdgcn_s_setprio(0);                                              \
    WAIT_STMT;                                                                  \
    __builtin_amdgcn_sched_barrier(0);                                          \
    __builtin_amdgcn_s_barrier();                                               \
    __builtin_amdgcn_sched_barrier(0);                                          \
  }

__global__ __launch_bounds__(512, 2)
void gemm8(const unsigned short* __restrict__ A, const unsigned short* __restrict__ B,
           const float* __restrict__ bias, const float* __restrict__ resid,
           float* __restrict__ Cf, unsigned short* __restrict__ Cb,
           int M, int N, int K, int relu) {
  extern __shared__ char smem[];   // 144 KB: 3 bufs x (A 32K + B 16K)

  const int t = threadIdx.x;
  const int lane = t & 63;
  const int wv = t >> 6;
  const int wm = wv >> 1;
  const int wn = wv & 1;
  const int fr = lane & 15;
  const int fq = lane >> 4;

  const int nwg = gridDim.x;
  const int orig = blockIdx.x;
  const int q8 = nwg >> 3;
  const int wgid = (orig & 7) * q8 + (orig >> 3);
  const int stid = wgid >> 4, within = wgid & 15;
  const int sm = within & 3, sn = within >> 2;
  const int Msup = M >> 10;
  const int stm = stid % Msup, stn = stid / Msup;
  const int m0 = (stm * 4 + sm) * 256;
  const int n0 = (stn * 4 + sn) * 128;

  f32x4 acc[4][4];
#pragma unroll
  for (int m = 0; m < 4; ++m)
#pragma unroll
    for (int n = 0; n < 4; ++n) acc[m][n] = (f32x4){0.f, 0.f, 0.f, 0.f};

  const int nk = K / 64;
  const int nj = nk / 2;

  stageB2(B, smem, 0, n0, K, 0, wv, lane);
  stageA (A, smem, 0, m0, K, 0, wv, lane);
  stageB2(B, smem, 1, n0, K, 1, wv, lane);
  stageA (A, smem, 1, m0, K, 1, wv, lane);
  VM6;
  __builtin_amdgcn_sched_barrier(0);
  __builtin_amdgcn_s_barrier();
  __builtin_amdgcn_sched_barrier(0);

  for (int j = 0; j < nj - 1; ++j) {
    const int k0 = 2 * j, k1 = 2 * j + 1;
    const int s0k = k0 + 2, s1k = k1 + 2;
    const int b0 = k0 % 3, b1 = k1 % 3;
    const int sb0 = s0k % 3, sb1 = s1k % 3;
    bf16x8 bfr[4][2];
    DO_PHASE(b0, 0, true,  stageB2(B, smem, sb0, n0, K, s0k, wv, lane), );
    DO_PHASE(b0, 2, false, stageA (A, smem, sb0, m0, K, s0k, wv, lane), VM6);
    DO_PHASE(b1, 0, true,  stageB2(B, smem, sb1, n0, K, s1k, wv, lane), );
    DO_PHASE(b1, 2, false, stageA (A, smem, sb1, m0, K, s1k, wv, lane), VM6);
  }
  {
    const int b0 = (nk - 2) % 3, b1 = (nk - 1) % 3;
    bf16x8 bfr[4][2];
    DO_PHASE(b0, 0, true,  , );
    DO_PHASE(b0, 2, false, , VM0);
    DO_PHASE(b1, 0, true,  , );
    DO_PHASE(b1, 2, false, , );
  }

  float* slab = (float*)(smem + wv * 4352);
#pragma unroll
  for (int m = 0; m < 4; ++m) {
#pragma unroll
    for (int n = 0; n < 4; ++n)
#pragma unroll
      for (int j = 0; j < 4; ++j)
        slab[(fq * 4 + j) * 68 + n * 16 + fr] = acc[m][n][j];
    int rg0 = m0 + wm * 64 + m * 16;
#pragma unroll
    for (int it = 0; it < 4; ++it) {
      int u = it * 64 + lane;
      int row = u >> 4, seg = u & 15;
      float4 v = *(const float4*)&slab[row * 68 + seg * 4];
      int col = n0 + wn * 64 + seg * 4;
      float4 b4 = *(const float4*)&bias[col];
      v.x += b4.x; v.y += b4.y; v.z += b4.z; v.w += b4.w;
      if (relu) {
        v.x = fmaxf(v.x, 0.f); v.y = fmaxf(v.y, 0.f);
        v.z = fmaxf(v.z, 0.f); v.w = fmaxf(v.w, 0.f);
      }
      size_t idx = (size_t)(rg0 + row) * N + col;
      if (resid) {
        float4 r4 = *(const float4*)&resid[idx];
        v.x += r4.x; v.y += r4.y; v.z += r4.z; v.w += r4.w;
      }
      if (Cf) {
        *(float4*)&Cf[idx] = v;
      } else {
        ushort4 ob;
        ob.x = f2bf(v.x); ob.y = f2bf(v.y); ob.z = f2bf(v.z); ob.w = f2bf(v.w);
        *(ushort4*)&Cb[idx] = ob;
      }
    }
  }
}

// ---------------------------------------------------------------------------
// V transpose: qkvb V-part -> vtb [(bh*64 + d)][s].
// ---------------------------------------------------------------------------
__global__ __launch_bounds__(256)
void vtrans_kernel(const unsigned short* __restrict__ qkvb, unsigned short* __restrict__ vtb) {
  __shared__ __align__(16) unsigned short tile[64][64];
  const int st = blockIdx.x;
  const int bh = blockIdx.y;
  const int b = bh >> 4, h = bh & 15;
  const int t = threadIdx.x;
#pragma unroll
  for (int p = 0; p < 2; ++p) {
    int item = p * 256 + t;
    int r = item >> 3, c8 = item & 7;
    const unsigned short* src =
        qkvb + (size_t)(b * SEQ + st * 64 + r) * (3 * DMODEL) + 2048 + h * 64 + c8 * 8;
    *(uint4*)&tile[r][(c8 ^ (r & 7)) * 8] = *(const uint4*)src;
  }
  __syncthreads();
#pragma unroll
  for (int p = 0; p < 2; ++p) {
    int item = p * 256 + t;
    int d = item & 63, s8 = item >> 6;
    unsigned short v[8];
#pragma unroll
    for (int e = 0; e < 8; ++e) {
      int s = s8 * 8 + e;
      v[e] = tile[s][(((d >> 3) ^ (s & 7)) * 8) + (d & 7)];
    }
    uint4 u;
    u.x = (unsigned int)v[0] | ((unsigned int)v[1] << 16);
    u.y = (unsigned int)v[2] | ((unsigned int)v[3] << 16);
    u.z = (unsigned int)v[4] | ((unsigned int)v[5] << 16);
    u.w = (unsigned int)v[6] | ((unsigned int)v[7] << 16);
    *(uint4*)(vtb + ((size_t)bh * 64 + d) * SEQ + st * 64 + s8 * 8) = u;
  }
}

// ---------------------------------------------------------------------------
// MFMA flash attention v5 (round-9 structure, passing, unchanged).
// ---------------------------------------------------------------------------
__global__ __launch_bounds__(512, 4)
void attn_kernel(const unsigned short* __restrict__ qkv, const unsigned short* __restrict__ vtb,
                 unsigned short* __restrict__ ctxb) {
  __shared__ __align__(16) unsigned short Ks[2][64][64];
  __shared__ __align__(16) unsigned short Vts[2][64][64];
  __shared__ __align__(16) unsigned short Slab[8][32][64];

  const int t = threadIdx.x;
  const int lane = t & 63;
  const int wq = t >> 6;
  const int l31 = lane & 31;
  const int hi1 = lane >> 5;
  const int bid = blockIdx.x;
  const int bh = bid & 63;
  const int qt = bid >> 6;
  const int b = bh >> 4, h = bh & 15;
  const int q0 = qt * 256;

  const size_t RS = 3 * DMODEL;
  const unsigned short* qb = qkv + (size_t)b * SEQ * RS + h * DHEAD;
  const unsigned short* kb = qb + DMODEL;

  bf16x8 qf[4];
  {
    const unsigned short* qrow = qb + (size_t)(q0 + wq * 32 + l31) * RS;
#pragma unroll
    for (int s = 0; s < 4; ++s)
      qf[s] = *(const bf16x8*)(qrow + s * 16 + hi1 * 8);
  }

  const unsigned short* kgl =
      kb + (size_t)(wq * 8 + (lane >> 3)) * RS + ((lane & 7) ^ (lane >> 3)) * 8;
  const unsigned short* vgl =
      vtb + ((size_t)bh * 64 + wq * 8 + (lane >> 3)) * SEQ + ((lane & 7) ^ (lane >> 3)) * 8;

  f32x16 oacc[2] = {};
  float lacc = 0.f;

  gload16(kgl, (char*)&Ks[0][wq * 8][0]);
  gload16(vgl, (char*)&Vts[0][wq * 8][0]);
  __syncthreads();

  const float C = 0.18033688011112042f;   // 0.125 * log2(e)

  for (int kt = 0; kt < NT; ++kt) {
    const int cur = kt & 1;
    if (kt + 1 < NT) {
      gload16(kgl + (size_t)(kt + 1) * 64 * RS, (char*)&Ks[cur ^ 1][wq * 8][0]);
      gload16(vgl + (size_t)(kt + 1) * 64, (char*)&Vts[cur ^ 1][wq * 8][0]);
    }

    f32x16 sacc[2] = {};
    __builtin_amdgcn_s_setprio(1);
#pragma unroll
    for (int s = 0; s < 4; ++s) {
#pragma unroll
      for (int kvt = 0; kvt < 2; ++kvt) {
        int row = kvt * 32 + l31;
        bf16x8 kf = *(const bf16x8*)&Ks[cur][row][(((2 * s + hi1) ^ (row & 7)) * 8)];
        sacc[kvt] = __builtin_amdgcn_mfma_f32_32x32x16_bf16(kf, qf[s], sacc[kvt], 0, 0, 0);
      }
    }
    __builtin_amdgcn_s_setprio(0);

#pragma unroll
    for (int kvt = 0; kvt < 2; ++kvt) {
      float p[16];
#pragma unroll
      for (int r = 0; r < 16; ++r) p[r] = fexp2(sacc[kvt][r] * C);
      float ps = 0.f;
#pragma unroll
      for (int r = 0; r < 16; ++r) ps += p[r];
      lacc += ps;
#pragma unroll
      for (int half = 0; half < 2; ++half) {
        const int lo = half * 8;
        unsigned int x0 = cvtpk(p[lo + 0], p[lo + 1]);
        unsigned int x1 = cvtpk(p[lo + 2], p[lo + 3]);
        unsigned int y0 = cvtpk(p[lo + 4], p[lo + 5]);
        unsigned int y1 = cvtpk(p[lo + 6], p[lo + 7]);
        plswap(x0, y0);
        plswap(x1, y1);
        bf16x8 pa = __builtin_bit_cast(bf16x8, (u32x4){x0, x1, y0, y1});
        const int s2 = kvt * 2 + half;
        __builtin_amdgcn_s_setprio(1);
#pragma unroll
        for (int dt = 0; dt < 2; ++dt) {
          int vrow = dt * 32 + l31;
          bf16x8 vf = *(const bf16x8*)&Vts[cur][vrow][(((2 * s2 + hi1) ^ (vrow & 7)) * 8)];
          oacc[dt] = __builtin_amdgcn_mfma_f32_32x32x16_bf16(pa, vf, oacc[dt], 0, 0, 0);
        }
        __builtin_amdgcn_s_setprio(0);
      }
    }
    __syncthreads();
  }

  lacc += __shfl_xor(lacc, 32);
  float inv = 1.0f / lacc;

  float iv[16];
#pragma unroll
  for (int r = 0; r < 16; ++r)
    iv[r] = __shfl(inv, (r & 3) + 8 * (r >> 2) + 4 * hi1);

#pragma unroll
  for (int dt = 0; dt < 2; ++dt) {
    const int chunk = dt * 4 + (l31 >> 3);
    const int e7 = l31 & 7;
#pragma unroll
    for (int r = 0; r < 16; ++r) {
      int qp = (r & 3) + 8 * (r >> 2) + 4 * hi1;
      Slab[wq][qp][((chunk ^ (qp & 7)) * 8) + e7] = f2bf(oacc[dt][r] * iv[r]);
    }
  }
#pragma unroll
  for (int it = 0; it < 4; ++it) {
    int u = it * 64 + lane;
    int row = u >> 3, s = u & 7;
    uint4 v = *(const uint4*)&Slab[wq][row][((s ^ (row & 7)) * 8)];
    *(uint4*)(ctxb + (size_t)(b * SEQ + q0 + wq * 32 + row) * DMODEL + h * DHEAD + s * 8) = v;
  }
}

// ---------------------------------------------------------------------------
// LayerNorm with optional secondary bf16 output.
// ---------------------------------------------------------------------------
__global__ __launch_bounds__(256)
void ln_kernel(const float* __restrict__ Z, const float* __restrict__ g,
               const float* __restrict__ bta, float* __restrict__ Y,
               unsigned short* __restrict__ Yb) {
  const int row = blockIdx.x;
  const float4* z4 = (const float4*)(Z + (size_t)row * DMODEL);
  float4 v = z4[threadIdx.x];
  float s = v.x + v.y + v.z + v.w;
  float ss = fmaf(v.x, v.x, fmaf(v.y, v.y, fmaf(v.z, v.z, v.w * v.w)));
#pragma unroll
  for (int o = 32; o >= 1; o >>= 1) {
    s += __shfl_xor(s, o);
    ss += __shfl_xor(ss, o);
  }
  __shared__ float red[8];
  int w = threadIdx.x >> 6;
  if ((threadIdx.x & 63) == 0) { red[w] = s; red[4 + w] = ss; }
  __syncthreads();
  s = red[0] + red[1] + red[2] + red[3];
  ss = red[4] + red[5] + red[6] + red[7];
  float mu = s * (1.0f / DMODEL);
  float var = ss * (1.0f / DMODEL) - mu * mu;
  float rs = rsqrtf(var + LNEPS);
  float4 gg = ((const float4*)g)[threadIdx.x];
  float4 bb = ((const float4*)bta)[threadIdx.x];
  float4 o;
  o.x = (v.x - mu) * rs * gg.x + bb.x;
  o.y = (v.y - mu) * rs * gg.y + bb.y;
  o.z = (v.z - mu) * rs * gg.z + bb.z;
  o.w = (v.w - mu) * rs * gg.w + bb.w;
  ((float4*)(Y + (size_t)row * DMODEL))[threadIdx.x] = o;
  if (Yb) {
    ushort4 ob;
    ob.x = f2bf(o.x); ob.y = f2bf(o.y); ob.z = f2bf(o.z); ob.w = f2bf(o.w);
    ((ushort4*)(Yb + (size_t)row * DMODEL))[threadIdx.x] = ob;
  }
}

// ---------------------------------------------------------------------------
extern "C" void kernel_launch(void* const* d_in, const int* in_sizes, int n_in,
                              void* d_out, int out_size, void* d_ws, size_t ws_size,
                              hipStream_t stream) {
  const int* tokens       = (const int*)d_in[0];
  const float* emb        = (const float*)d_in[1];
  const float* in_proj_w  = (const float*)d_in[2];
  const float* in_proj_b  = (const float*)d_in[3];
  const float* out_proj_w = (const float*)d_in[4];
  const float* out_proj_b = (const float*)d_in[5];
  const float* w1         = (const float*)d_in[6];
  const float* b1         = (const float*)d_in[7];
  const float* w2         = (const float*)d_in[8];
  const float* b2         = (const float*)d_in[9];
  const float* g1         = (const float*)d_in[10];
  const float* beta1      = (const float*)d_in[11];
  const float* g2         = (const float*)d_in[12];
  const float* beta2      = (const float*)d_in[13];
  float* out = (float*)d_out;

  char* ws = (char*)d_ws;
  const size_t MB = 1ull << 20;
  unsigned short* inwb  = (unsigned short*)(ws + 0 * MB);
  unsigned short* outwb = (unsigned short*)(ws + 6 * MB);
  unsigned short* w1b   = (unsigned short*)(ws + 8 * MB);
  unsigned short* w2b   = (unsigned short*)(ws + 16 * MB);
  float* x              = (float*)(ws + 24 * MB);
  unsigned short* xb    = (unsigned short*)(ws + 56 * MB);
  unsigned short* qkvb  = (unsigned short*)(ws + 72 * MB);
  unsigned short* vtb   = (unsigned short*)(ws + 120 * MB);
  unsigned short* ctxb  = (unsigned short*)(ws + 56 * MB);
  float* h              = (float*)(ws + 72 * MB);
  unsigned short* hb    = (unsigned short*)(ws + 104 * MB);
  unsigned short* ffbb  = (unsigned short*)(ws + 120 * MB);
  float* y2             = (float*)(ws + 24 * MB);

  const size_t GLDS8 = 147456;    // gemm8: 144 KB
  const size_t GLDSP = 131072;    // gemm8p: 128 KB

  embed_kernel<<<(MROWS * (DMODEL / 2) + 255) / 256, 256, 0, stream>>>(tokens, emb, x, xb);
  cvt4_kernel<<<12288, 256, 0, stream>>>(in_proj_w, out_proj_w, w1, w2,
                                         inwb, outwb, w1b, w2b);
  // qkv = x @ in_proj_w^T + b  (bf16 out)   [384 blocks, 8-phase]
  gemm8p<<<(MROWS / 256) * (3 * DMODEL / 256), 512, GLDSP, stream>>>(
      xb, inwb, in_proj_b, nullptr, nullptr, qkvb, MROWS, 3 * DMODEL, DMODEL, 0);
  // V^T pre-transpose
  vtrans_kernel<<<dim3(SEQ / 64, BATCH * NH), 256, 0, stream>>>(qkvb, vtb);
  // flash attention v5 -> ctxb (bf16)
  attn_kernel<<<(SEQ / 256) * (BATCH * NH), 512, 0, stream>>>(qkvb, vtb, ctxb);
  // h = ctx @ out_proj_w^T + b + x  (f32 out)   [256 blocks]
  gemm8<<<(MROWS / 256) * (DMODEL / 128), 512, GLDS8, stream>>>(
      ctxb, outwb, out_proj_b, x, h, nullptr, MROWS, DMODEL, DMODEL, 0);
  ln_kernel<<<MROWS, 256, 0, stream>>>(h, g1, beta1, h, hb);
  // ffb = relu(h @ w1^T + b1)  (bf16 out)   [512 blocks, 8-phase]
  gemm8p<<<(MROWS / 256) * (DFF / 256), 512, GLDSP, stream>>>(
      hb, w1b, b1, nullptr, nullptr, ffbb, MROWS, DFF, DMODEL, 1);
  // y2 = ffb @ w2^T + b2 + h  (f32 out)   [256 blocks]
  gemm8<<<(MROWS / 256) * (DMODEL / 128), 512, GLDS8, stream>>>(
      ffbb, w2b, b2, h, y2, nullptr, MROWS, DMODEL, DFF, 0);
  ln_kernel<<<MROWS, 256, 0, stream>>>(y2, g2, beta2, out, nullptr);
}